// Round 1
// baseline (969.034 us; speedup 1.0000x reference)
//
#include <hip/hip_runtime.h>
#include <cstdint>
#include <cstddef>

// ---- model constants ----
#define NEG_SLOPE 0.2f
#define RRELU_SLOPE 0.22916666666666666f  // (1/8 + 1/3)/2, eval-mode rrelu

__device__ __forceinline__ float wave_max64(float v) {
#pragma unroll
  for (int o = 32; o > 0; o >>= 1) v = fmaxf(v, __shfl_xor(v, o, 64));
  return v;
}
__device__ __forceinline__ float wave_sum64(float v) {
#pragma unroll
  for (int o = 32; o > 0; o >>= 1) v += __shfl_xor(v, o, 64);
  return v;
}

// ---------------- CSR build ----------------
__global__ __launch_bounds__(256) void count_kernel(const int* __restrict__ dst, int E, int N,
                                                    int* __restrict__ cnt) {
  int i = blockIdx.x * 256 + threadIdx.x;
  if (i >= E + N) return;
  int d = (i < E) ? dst[i] : (i - E);  // tail = self loops
  atomicAdd(&cnt[d], 1);
}

// block scans 2048 elements (256 threads x 8)
__global__ __launch_bounds__(256) void scanA(const int* __restrict__ cnt, int N,
                                             int* __restrict__ rp, int* __restrict__ sums) {
  __shared__ int lds[256];
  int tid = threadIdx.x;
  int base = blockIdx.x * 2048 + tid * 8;
  int v[8];
  int s = 0;
#pragma unroll
  for (int j = 0; j < 8; j++) {
    int idx = base + j;
    v[j] = (idx < N) ? cnt[idx] : 0;
    s += v[j];
  }
  lds[tid] = s;
  __syncthreads();
#pragma unroll
  for (int o = 1; o < 256; o <<= 1) {
    int t = (tid >= o) ? lds[tid - o] : 0;
    __syncthreads();
    lds[tid] += t;
    __syncthreads();
  }
  int off = (tid > 0) ? lds[tid - 1] : 0;
  if (tid == 255) sums[blockIdx.x] = lds[255];
  int run = off;
#pragma unroll
  for (int j = 0; j < 8; j++) {
    int idx = base + j;
    if (idx < N) rp[idx] = run;  // exclusive within block
    run += v[j];
  }
}

__global__ __launch_bounds__(64) void scanB(int* __restrict__ sums, int nb) {
  int lane = threadIdx.x;
  int v = (lane < nb) ? sums[lane] : 0;
  int inc = v;
#pragma unroll
  for (int o = 1; o < 64; o <<= 1) {
    int t = __shfl_up(inc, o, 64);
    if (lane >= o) inc += t;
  }
  if (lane < nb) sums[lane] = inc - v;  // exclusive
}

__global__ __launch_bounds__(256) void scanC(int* __restrict__ rp, const int* __restrict__ sums,
                                             int N, int total) {
  int i = blockIdx.x * 256 + threadIdx.x;
  if (i < N) rp[i] += sums[i >> 11];
  if (i == 0) rp[N] = total;
}

__global__ __launch_bounds__(256) void fill_kernel(const int* __restrict__ src,
                                                   const int* __restrict__ dst, int E, int N,
                                                   int* __restrict__ pos, int* __restrict__ col) {
  int i = blockIdx.x * 256 + threadIdx.x;
  if (i >= E + N) return;
  int s, d;
  if (i < E) { s = src[i]; d = dst[i]; }
  else       { s = d = i - E; }
  int slot = atomicAdd(&pos[d], 1);
  col[slot] = s;
}

// ---------------- GEMM: out[N,192] = A[N,K] @ W[K,192], 64x64 tiles ----------------
template <int K, bool CONCAT>
__global__ __launch_bounds__(256) void gemm_kernel(const float* __restrict__ A0,
                                                   const float* __restrict__ A1,
                                                   const float* __restrict__ W,
                                                   float* __restrict__ out, int N) {
  __shared__ float As[64][K + 4];
  __shared__ float Ws[K][64];
  const int m0 = blockIdx.x * 64;
  const int c0 = blockIdx.y * 64;
  const int tid = threadIdx.x;

  // load A tile: 64 rows x K floats
#pragma unroll
  for (int i = 0; i < K / 16; i++) {
    int f = tid + 256 * i;        // float4 index
    int row = f / (K / 4);
    int c4 = f % (K / 4);
    int gr = m0 + row;
    float4 val = make_float4(0.f, 0.f, 0.f, 0.f);
    if (gr < N) {
      if (CONCAT) {
        if (c4 < 16) val = ((const float4*)(A0 + (size_t)gr * 64))[c4];
        else         val = ((const float4*)(A1 + (size_t)gr * 64))[c4 - 16];
      } else {
        val = ((const float4*)(A0 + (size_t)gr * K))[c4];
      }
    }
    *(float4*)&As[row][c4 * 4] = val;
  }
  // load W tile: K rows x 64 cols (global row stride 192)
#pragma unroll
  for (int i = 0; i < K / 16; i++) {
    int f = tid + 256 * i;
    int row = f / 16;
    int cq = f % 16;
    *(float4*)&Ws[row][cq * 4] = *(const float4*)(W + (size_t)row * 192 + c0 + cq * 4);
  }
  __syncthreads();

  const int tx = tid & 15;   // col group: cols c0 + tx*4 .. +3
  const int ty = tid >> 4;   // row group: rows m0 + ty*4 .. +3
  float4 acc[4];
#pragma unroll
  for (int i = 0; i < 4; i++) acc[i] = make_float4(0.f, 0.f, 0.f, 0.f);

  for (int k0 = 0; k0 < K; k0 += 4) {
    float4 b0 = *(float4*)&Ws[k0 + 0][tx * 4];
    float4 b1 = *(float4*)&Ws[k0 + 1][tx * 4];
    float4 b2 = *(float4*)&Ws[k0 + 2][tx * 4];
    float4 b3 = *(float4*)&Ws[k0 + 3][tx * 4];
#pragma unroll
    for (int i = 0; i < 4; i++) {
      float4 a = *(float4*)&As[ty * 4 + i][k0];
      acc[i].x += b0.x * a.x + b1.x * a.y + b2.x * a.z + b3.x * a.w;
      acc[i].y += b0.y * a.x + b1.y * a.y + b2.y * a.z + b3.y * a.w;
      acc[i].z += b0.z * a.x + b1.z * a.y + b2.z * a.z + b3.z * a.w;
      acc[i].w += b0.w * a.x + b1.w * a.y + b2.w * a.z + b3.w * a.w;
    }
  }
#pragma unroll
  for (int i = 0; i < 4; i++) {
    int row = m0 + ty * 4 + i;
    if (row < N) *(float4*)(out + (size_t)row * 192 + c0 + tx * 4) = acc[i];
  }
}

// ---------------- per-node attention logits s,d ----------------
__global__ __launch_bounds__(256) void sd_kernel(const float* __restrict__ xl,
                                                 const float* __restrict__ asrc,
                                                 const float* __restrict__ adst,
                                                 float* __restrict__ sd, int N) {
  int wave = threadIdx.x >> 6, lane = threadIdx.x & 63;
  int n = blockIdx.x * 4 + wave;
  if (n >= N) return;
  const float* p = xl + (size_t)n * 192;
  float x0 = p[lane], x1 = p[64 + lane], x2 = p[128 + lane];
  float s0 = wave_sum64(x0 * asrc[lane]);
  float s1 = wave_sum64(x1 * asrc[64 + lane]);
  float s2 = wave_sum64(x2 * asrc[128 + lane]);
  float d0 = wave_sum64(x0 * adst[lane]);
  float d1 = wave_sum64(x1 * adst[64 + lane]);
  float d2 = wave_sum64(x2 * adst[128 + lane]);
  if (lane == 0) {
    float* o = sd + (size_t)n * 6;
    o[0] = s0; o[1] = s1; o[2] = s2; o[3] = d0; o[4] = d1; o[5] = d2;
  }
}

// ---------------- aggregation: wave per dst node, online softmax ----------------
// MODE 1: mean over heads + bias1 + rrelu -> h1[N,64]
// MODE 2: concat + bias2 + rrelu + dot(lin_w) + lin_b -> out[N]
template <int MODE>
__global__ __launch_bounds__(256) void agg_kernel(const float* __restrict__ xl,
                                                  const float* __restrict__ sd,
                                                  const int* __restrict__ rp,
                                                  const int* __restrict__ col,
                                                  const float* __restrict__ bias,
                                                  const float* __restrict__ lw,
                                                  const float* __restrict__ lb,
                                                  float* __restrict__ out, int N) {
  int wave = threadIdx.x >> 6, lane = threadIdx.x & 63;
  int n = blockIdx.x * 4 + wave;
  if (n >= N) return;
  int beg = rp[n], end = rp[n + 1];
  const float* sdn = sd + (size_t)n * 6;
  float d0 = sdn[3], d1 = sdn[4], d2 = sdn[5];
  float m0 = -INFINITY, m1 = -INFINITY, m2 = -INFINITY;
  float l0 = 0.f, l1 = 0.f, l2 = 0.f;
  float a0 = 0.f, a1 = 0.f, a2 = 0.f;

  for (int j0 = beg; j0 < end; j0 += 64) {
    int cntc = min(64, end - j0);
    bool valid = lane < cntc;
    int srcv = valid ? col[j0 + lane] : 0;
    float al0 = -INFINITY, al1 = -INFINITY, al2 = -INFINITY;
    if (valid) {
      const float* sp = sd + (size_t)srcv * 6;
      float t0 = sp[0] + d0, t1 = sp[1] + d1, t2 = sp[2] + d2;
      al0 = (t0 < 0.f) ? t0 * NEG_SLOPE : t0;
      al1 = (t1 < 0.f) ? t1 * NEG_SLOPE : t1;
      al2 = (t2 < 0.f) ? t2 * NEG_SLOPE : t2;
    }
    float nm0 = fmaxf(m0, wave_max64(al0));
    float nm1 = fmaxf(m1, wave_max64(al1));
    float nm2 = fmaxf(m2, wave_max64(al2));
    float sc0 = expf(m0 - nm0), sc1 = expf(m1 - nm1), sc2 = expf(m2 - nm2);
    l0 *= sc0; l1 *= sc1; l2 *= sc2;
    a0 *= sc0; a1 *= sc1; a2 *= sc2;
    float e0 = valid ? expf(al0 - nm0) : 0.f;
    float e1 = valid ? expf(al1 - nm1) : 0.f;
    float e2 = valid ? expf(al2 - nm2) : 0.f;
    l0 += wave_sum64(e0);
    l1 += wave_sum64(e1);
    l2 += wave_sum64(e2);
    m0 = nm0; m1 = nm1; m2 = nm2;

    for (int j = 0; j < cntc; j++) {
      int sj = __shfl(srcv, j, 64);
      float w0 = __shfl(e0, j, 64);
      float w1 = __shfl(e1, j, 64);
      float w2 = __shfl(e2, j, 64);
      const float* p = xl + (size_t)sj * 192 + lane;
      a0 += p[0] * w0;
      a1 += p[64] * w1;
      a2 += p[128] * w2;
    }
  }

  float v0 = a0 / (l0 + 1e-16f);
  float v1 = a1 / (l1 + 1e-16f);
  float v2 = a2 / (l2 + 1e-16f);
  if (MODE == 1) {
    float r = (v0 + v1 + v2) / 3.0f + bias[lane];
    r = (r < 0.f) ? r * RRELU_SLOPE : r;
    out[(size_t)n * 64 + lane] = r;
  } else {
    v0 += bias[lane];       v0 = (v0 < 0.f) ? v0 * RRELU_SLOPE : v0;
    v1 += bias[64 + lane];  v1 = (v1 < 0.f) ? v1 * RRELU_SLOPE : v1;
    v2 += bias[128 + lane]; v2 = (v2 < 0.f) ? v2 * RRELU_SLOPE : v2;
    float part = v0 * lw[lane] + v1 * lw[64 + lane] + v2 * lw[128 + lane];
    part = wave_sum64(part);
    if (lane == 0) out[n] = part + lb[0];
  }
}

extern "C" void kernel_launch(void* const* d_in, const int* in_sizes, int n_in,
                              void* d_out, int out_size, void* d_ws, size_t ws_size,
                              hipStream_t stream) {
  const float* z   = (const float*)d_in[0];
  const float* x   = (const float*)d_in[1];
  const int*   ei  = (const int*)d_in[2];
  const float* W1  = (const float*)d_in[3];
  const float* as1 = (const float*)d_in[4];
  const float* ad1 = (const float*)d_in[5];
  const float* b1  = (const float*)d_in[6];
  const float* W2  = (const float*)d_in[7];
  const float* as2 = (const float*)d_in[8];
  const float* ad2 = (const float*)d_in[9];
  const float* b2  = (const float*)d_in[10];
  const float* lw  = (const float*)d_in[11];
  const float* lb  = (const float*)d_in[12];
  float* out = (float*)d_out;

  const int N = in_sizes[0] / 64;
  const int E = in_sizes[2] / 2;
  const int* srcA = ei;
  const int* dstA = ei + E;

  char* ws = (char*)d_ws;
  size_t off = 0;
  auto alloc = [&](size_t bytes) -> void* {
    void* p = ws + off;
    off = (off + bytes + 255) & ~(size_t)255;
    return p;
  };
  float* xl  = (float*)alloc((size_t)N * 192 * 4);
  float* h1  = (float*)alloc((size_t)N * 64 * 4);
  float* sdv = (float*)alloc((size_t)N * 6 * 4);
  int* rp    = (int*)alloc((size_t)(N + 1) * 4);
  int* pos   = (int*)alloc((size_t)N * 4);
  int* cnt   = (int*)alloc((size_t)N * 4);
  int* col   = (int*)alloc((size_t)(E + N) * 4);
  int* sums  = (int*)alloc(64 * 4);
  if (off > ws_size) return;  // workspace too small; fail loudly via poisoned output

  const int tot = E + N;
  hipMemsetAsync(cnt, 0, (size_t)N * 4, stream);
  count_kernel<<<(tot + 255) / 256, 256, 0, stream>>>(dstA, E, N, cnt);
  const int nb = (N + 2047) / 2048;  // 49 for N=100000 (<=64)
  scanA<<<nb, 256, 0, stream>>>(cnt, N, rp, sums);
  scanB<<<1, 64, 0, stream>>>(sums, nb);
  scanC<<<(N + 255) / 256, 256, 0, stream>>>(rp, sums, N, tot);
  hipMemcpyAsync(pos, rp, (size_t)N * 4, hipMemcpyDeviceToDevice, stream);
  fill_kernel<<<(tot + 255) / 256, 256, 0, stream>>>(srcA, dstA, E, N, pos, col);

  dim3 gg((N + 63) / 64, 3);
  // layer 1
  gemm_kernel<128, true><<<gg, 256, 0, stream>>>(z, x, W1, xl, N);
  sd_kernel<<<(N + 3) / 4, 256, 0, stream>>>(xl, as1, ad1, sdv, N);
  agg_kernel<1><<<(N + 3) / 4, 256, 0, stream>>>(xl, sdv, rp, col, b1, nullptr, nullptr, h1, N);
  // layer 2 (reuse xl buffer) + fused final linear
  gemm_kernel<64, false><<<gg, 256, 0, stream>>>(h1, nullptr, W2, xl, N);
  sd_kernel<<<(N + 3) / 4, 256, 0, stream>>>(xl, as2, ad2, sdv, N);
  agg_kernel<2><<<(N + 3) / 4, 256, 0, stream>>>(xl, sdv, rp, col, b2, lw, lb, out, N);
}